// Round 6
// baseline (161.051 us; speedup 1.0000x reference)
//
#include <hip/hip_runtime.h>
#include <math.h>

// Problem constants (match reference)
constexpr int NB = 32, NM = 64, NK = 8400, NC = 80, NT = 15;
constexpr int NQ = 4, KQ = 2100;       // k split into 4 quarters of 2100
constexpr float FEPS = 1e-7f;

// Output layout: [tso | tgt_bboxes | assign | overlaps | fg], all float32
constexpr size_t OUT_TSO = 0;
constexpr size_t OUT_TGT = (size_t)NB * NK * NC;            // 21504000
constexpr size_t OUT_ASN = OUT_TGT + (size_t)NB * NK * 4;   // 22579200
constexpr size_t OUT_OVL = OUT_ASN + (size_t)NB * NM * NK;  // 39782400
constexpr size_t OUT_FG  = OUT_OVL + (size_t)NB * NM * NK;  // 56985600

// ---------------------------------------------------------------------------
// kZ: workspace init (replaces pathologically slow graph-captured memset).
// mikey=0, fg0=0, slot=-1, flag=0. 4.3 MB grid-stride, full BW.
// ---------------------------------------------------------------------------
__global__ __launch_bounds__(256) void kZ(unsigned long long* __restrict__ mikey,
                                          int* __restrict__ fg0,
                                          int* __restrict__ slot,
                                          int* __restrict__ flag)
{
  const int n = NB * NK;
  for (int i = blockIdx.x * 256 + threadIdx.x; i < n; i += gridDim.x * 256) {
    mikey[i] = 0ULL;
    fg0[i] = 0;
    slot[i] = -1;
  }
  if (blockIdx.x == 0 && threadIdx.x == 0) *flag = 0;
}

// ---------------------------------------------------------------------------
// kA: one block per (b,m,quarter).
//   pass 1: zero LDS ov tile + point-in-box test -> positive-k list (~5%)
//   pass 2: CIoU on positives only -> s_ov, am candidates, mi atomicMax key
//   flush : dense coalesced overlaps write from s_ov (zeros included)
//   tail  : per-quarter top-15 (value desc, idx asc) by wave-0 butterfly
// ---------------------------------------------------------------------------
__global__ __launch_bounds__(256) void kA(
    const float* __restrict__ points, const float* __restrict__ gt_bboxes,
    const int* __restrict__ gt_labels, const float* __restrict__ pred_bboxes,
    const float* __restrict__ pred_scores, const int* __restrict__ gt_mask,
    float* __restrict__ out, float* __restrict__ candv, int* __restrict__ candi,
    float* __restrict__ ovmaxq, unsigned long long* __restrict__ mikey)
{
  __shared__ float s_ov[KQ];     // 8.4 KB dense overlaps tile
  __shared__ int   s_pos[KQ];    // 8.4 KB positive-k list
  __shared__ float s_cv[KQ];     // 8.4 KB candidate am
  __shared__ int   s_ci[KQ];     // 8.4 KB candidate k
  __shared__ int   s_np, s_cnt;
  __shared__ float s_m[4];

  const int bm = blockIdx.x;
  const int q  = blockIdx.y;
  const int b  = bm >> 6;
  const int m  = bm & 63;
  const int t  = threadIdx.x;
  const int wid = t >> 6, lane = t & 63;
  const int kbeg = q * KQ;

  float* cv = candv + (size_t)(bm * NQ + q) * NT;
  int*   ci = candi + (size_t)(bm * NQ + q) * NT;
  float* ovl_out = out + OUT_OVL + (size_t)bm * NK;

  const int maskv = gt_mask[bm];
  if (!maskv) {
    #pragma unroll
    for (int j = 0; j < 9; ++j) {
      const int idx = j * 256 + t;
      if (idx < KQ) ovl_out[kbeg + idx] = 0.f;
    }
    if (t == 0) ovmaxq[bm * NQ + q] = 0.f;
    if (t < NT) { cv[t] = 0.f; ci[t] = -1; }
    return;
  }
  if (t == 0) { s_np = 0; s_cnt = 0; }
  __syncthreads();

  const float4 g = *(const float4*)(gt_bboxes + (size_t)bm * 4);
  const int   label = gt_labels[bm];
  const float2* pts = (const float2*)points;

  // pass 1: zero ov tile + point-in-box (diff.max(-1) < 1e-6, exact f32 subs)
  #pragma unroll
  for (int j = 0; j < 9; ++j) {
    const int idx = j * 256 + t;
    if (idx < KQ) {
      s_ov[idx] = 0.f;
      const int k = kbeg + idx;
      float2 p = pts[k];
      float dmax = fmaxf(fmaxf(g.x - p.x, g.y - p.y), fmaxf(p.x - g.z, p.y - g.w));
      if (dmax < 1e-6f) { int e = atomicAdd(&s_np, 1); s_pos[e] = k; }
    }
  }
  __syncthreads();
  const int np = s_np;

  const float4* pb = (const float4*)(pred_bboxes + (size_t)b * NK * 4);
  const float*  ps = pred_scores + (size_t)b * NK * NC;
  unsigned long long* mk = mikey + (size_t)b * NK;

  const float w1 = g.z - g.x, h1 = g.w - g.y;
  const float at1 = atanf(w1 / (h1 + FEPS));
  const float area1 = w1 * h1;
  const float CV = (float)(4.0 / (M_PI * M_PI));
  const float ONE_EPS = (float)(1.0 + 1e-7);

  float lmax = 0.f;
  for (int e = t; e < np; e += 256) {
    const int k = s_pos[e];
    float4 qb = pb[k];
    float w2 = qb.z - qb.x, h2 = qb.w - qb.y;
    float iw = fmaxf(fminf(g.z, qb.z) - fmaxf(g.x, qb.x), 0.f);
    float ih = fmaxf(fminf(g.w, qb.w) - fmaxf(g.y, qb.y), 0.f);
    float inter = iw * ih;
    float uni = area1 + w2 * h2 - inter + FEPS;
    float iou = inter / uni;
    float cw = fmaxf(g.z, qb.z) - fminf(g.x, qb.x);
    float ch = fmaxf(g.w, qb.w) - fminf(g.y, qb.y);
    float c2 = cw * cw + ch * ch + FEPS;
    float ex = qb.x + qb.z - g.x - g.z;
    float ey = qb.y + qb.w - g.y - g.w;
    float rho2 = (ex * ex + ey * ey) * 0.25f;
    float dat = atanf(w2 / (h2 + FEPS)) - at1;
    float v = CV * dat * dat;
    float alpha = v / (v - iou + ONE_EPS);
    float ciou = iou - (rho2 / c2 + alpha * v);
    float ov = fmaxf(ciou, 0.f);
    if (ov > 0.f) {
      s_ov[k - kbeg] = ov;
      unsigned long long key =
          ((unsigned long long)__float_as_uint(ov) << 32) |
          (unsigned long long)(NM - 1 - m);             // value desc, first-m tie
      atomicMax(&mk[k], key);
      lmax = fmaxf(lmax, ov);
      float ts = ps[(size_t)k * NC + label];
      float o2 = ov * ov;
      float am = ts * (o2 * o2 * o2);                   // ts**1 * ov**6
      if (am > 1e-9f) {                                 // below cutoff never selected
        int p2 = atomicAdd(&s_cnt, 1);
        s_cv[p2] = am; s_ci[p2] = k;
      }
    }
  }
  __syncthreads();   // finalizes s_ov and s_cv/s_ci

  // dense coalesced overlaps flush (zeros + positives)
  #pragma unroll
  for (int j = 0; j < 9; ++j) {
    const int idx = j * 256 + t;
    if (idx < KQ) ovl_out[kbeg + idx] = s_ov[idx];
  }

  // partial row-max of overlaps
  float mv = lmax;
  #pragma unroll
  for (int d = 1; d < 64; d <<= 1) mv = fmaxf(mv, __shfl_xor(mv, d));
  if (lane == 0) s_m[wid] = mv;
  __syncthreads();
  if (t == 0)
    ovmaxq[bm * NQ + q] = fmaxf(fmaxf(s_m[0], s_m[1]), fmaxf(s_m[2], s_m[3]));

  if (wid != 0) return;           // extraction: wave 0 only
  const int n = s_cnt;

  // per-lane best over lane-strided slots; key = fbits(v)<<32 | ~ki
  unsigned long long bkey = 0; int bslot = -1;
  for (int e = lane; e < n; e += 64) {
    float v = s_cv[e];
    unsigned long long key =
        ((unsigned long long)__float_as_uint(v) << 32) |
        (unsigned long long)(0xFFFFFFFFu - (unsigned)s_ci[e]);
    if (key > bkey) { bkey = key; bslot = e; }
  }

  int it = 0;
  for (; it < NT; ++it) {
    unsigned long long wkey = bkey;
    #pragma unroll
    for (int d = 1; d < 64; d <<= 1) {
      unsigned long long ok = __shfl_xor(wkey, d);
      if (ok > wkey) wkey = ok;
    }
    if (wkey == 0) break;         // all consumed
    if (lane == 0) {
      cv[it] = __uint_as_float((unsigned)(wkey >> 32));
      ci[it] = (int)(0xFFFFFFFFu - (unsigned)wkey);
    }
    if (bkey == wkey) {           // unique winner (ki unique)
      s_cv[bslot] = -1.f;
      bkey = 0; bslot = -1;
      for (int e = lane; e < n; e += 64) {
        float v = s_cv[e];
        if (v >= 0.f) {
          unsigned long long key =
              ((unsigned long long)__float_as_uint(v) << 32) |
              (unsigned long long)(0xFFFFFFFFu - (unsigned)s_ci[e]);
          if (key > bkey) { bkey = key; bslot = e; }
        }
      }
    }
  }
  if (lane == 0)
    for (int r = it; r < NT; ++r) { cv[r] = 0.f; ci[r] = -1; }
}

// ---------------------------------------------------------------------------
// kA2: one wave per (b,m): merge 4x15 quarter candidates -> global top-15
// (identical ordering to single-pass iterative argmax), fg0/flag atomics,
// ovmax merge.
// ---------------------------------------------------------------------------
__global__ __launch_bounds__(64) void kA2(
    const float* __restrict__ candv, const int* __restrict__ candi,
    const float* __restrict__ ovmaxq, float* __restrict__ ovmaxp,
    int* __restrict__ tki, float* __restrict__ tkv,
    int* __restrict__ fg0, int* __restrict__ flag)
{
  __shared__ int   s_wi[NT];
  __shared__ float s_wv[NT];
  const int bm = blockIdx.x;
  const int b  = bm >> 6;
  const int lane = threadIdx.x;

  if (lane == 0) {
    const float* om = ovmaxq + bm * NQ;
    ovmaxp[bm] = fmaxf(fmaxf(om[0], om[1]), fmaxf(om[2], om[3]));
  }

  unsigned long long bkey = 0;
  if (lane < NQ * NT) {
    int ki = candi[(size_t)bm * NQ * NT + lane];
    if (ki >= 0) {
      float v = candv[(size_t)bm * NQ * NT + lane];
      bkey = ((unsigned long long)__float_as_uint(v) << 32) |
             (unsigned long long)(0xFFFFFFFFu - (unsigned)ki);
    }
  }

  int nf = 0;
  for (int it = 0; it < NT; ++it) {
    unsigned long long wkey = bkey;
    #pragma unroll
    for (int d = 1; d < 64; d <<= 1) {
      unsigned long long ok = __shfl_xor(wkey, d);
      if (ok > wkey) wkey = ok;
    }
    if (wkey == 0) break;
    if (bkey == wkey) {           // unique winner stores round result
      s_wv[it] = __uint_as_float((unsigned)(wkey >> 32));
      s_wi[it] = (int)(0xFFFFFFFFu - (unsigned)wkey);
      bkey = 0;
    }
    nf = it + 1;
  }
  __syncthreads();

  if (lane < NT) {
    if (lane < nf) {
      int fi = s_wi[lane];
      tki[bm * NT + lane] = fi;
      tkv[bm * NT + lane] = s_wv[lane];
      int old = atomicAdd(&fg0[(size_t)b * NK + fi], 1);
      if (old >= 1) atomicOr(flag, 1);
    } else {
      tki[bm * NT + lane] = -1;
      tkv[bm * NT + lane] = 0.f;
    }
  }
}

// ---------------------------------------------------------------------------
// kS: one block per b. Keep-filter + post-filter rowmax, then scatter the
// unique (m,k) assignments into slot/sval maps. Race-free: post-filter
// assignment is unique per k (flag -> mi filter; !flag -> fg0 <= 1).
// ---------------------------------------------------------------------------
__global__ __launch_bounds__(256) void kS(
    const int* __restrict__ tki, const float* __restrict__ tkv,
    const float* __restrict__ ovmaxp, const unsigned long long* __restrict__ mikey,
    const int* __restrict__ flagp, int* __restrict__ slot,
    float* __restrict__ sval)
{
  __shared__ unsigned char s_keep[NM * NT];
  __shared__ float s_rowmax[NM];

  const int b = blockIdx.x;
  const int t = threadIdx.x;
  const int flag = *flagp;
  const int base = b * NM * NT;

  for (int e = t; e < NM * NT; e += 256) {
    const int idx = tki[base + e];
    bool kp = (idx >= 0);
    if (kp && flag) {
      unsigned long long key = mikey[(size_t)b * NK + idx];
      kp = (NM - 1 - (int)(key & 0xFFFFFFFFull)) == e / NT;
    }
    s_keep[e] = kp;
  }
  __syncthreads();

  if (t < NM) {
    float r = 0.f;
    for (int j = 0; j < NT; ++j)
      if (s_keep[t * NT + j]) r = fmaxf(r, tkv[base + t * NT + j]);
    s_rowmax[t] = r;
  }
  __syncthreads();

  for (int e = t; e < NM * NT; e += 256) {
    if (!s_keep[e]) continue;
    const int m = e / NT;
    const int idx = tki[base + e];
    slot[b * NK + idx] = m;
    sval[b * NK + idx] = tkv[base + e] / (s_rowmax[m] + 1e-9f) * ovmaxp[b * NM + m];
  }
}

// ---------------------------------------------------------------------------
// kWt: streaming writer for tso (86 MB) + fg + tgt. Barrier-free, grid-stride.
// i -> (bk, c4); consecutive threads = consecutive c4 -> coalesced float4.
// ---------------------------------------------------------------------------
__global__ __launch_bounds__(256) void kWt(
    const int* __restrict__ slot, const float* __restrict__ sval,
    const int* __restrict__ gt_labels, const float* __restrict__ gt_bboxes,
    float* __restrict__ out)
{
  constexpr int C4 = NC / 4;           // 20
  const int tot = NB * NK * C4;
  float4* tso4 = (float4*)(out + OUT_TSO);
  float4* tgt4 = (float4*)(out + OUT_TGT);
  const float4* gtb = (const float4*)gt_bboxes;

  for (int i = blockIdx.x * 256 + threadIdx.x; i < tot; i += gridDim.x * 256) {
    const int bk = i / C4, c4 = i - bk * C4;
    const int s = slot[bk];
    float4 w = {0.f, 0.f, 0.f, 0.f};
    if (s >= 0) {
      const int lab = gt_labels[(bk / NK) * NM + s];
      const int c = c4 * 4;
      if (lab >= c && lab < c + 4) ((float*)&w)[lab - c] = sval[bk];
    }
    tso4[i] = w;
    if (c4 == 0) {
      out[OUT_FG + bk] = (s >= 0) ? 1.f : 0.f;          // OUT_FG + b*NK+k == +bk
      tgt4[bk] = gtb[(bk / NK) * NM + ((s >= 0) ? s : 0)];
    }
  }
}

// ---------------------------------------------------------------------------
// kWa: streaming writer for assign (68.8 MB). w = (slot[b,k]==m).
// slot rows are L2-hot (2.1 MB total, each reused 64x).
// ---------------------------------------------------------------------------
__global__ __launch_bounds__(256) void kWa(const int* __restrict__ slot,
                                           float* __restrict__ out)
{
  constexpr int K4 = NK / 4;           // 2100
  const int tot = NB * NM * K4;
  float4* asn4 = (float4*)(out + OUT_ASN);

  for (int i = blockIdx.x * 256 + threadIdx.x; i < tot; i += gridDim.x * 256) {
    const int c4 = i % K4;
    const int bm = i / K4;
    const int b = bm >> 6, m = bm & 63;
    int4 s4 = ((const int4*)(slot + b * NK))[c4];
    float4 w;
    w.x = (s4.x == m) ? 1.f : 0.f;
    w.y = (s4.y == m) ? 1.f : 0.f;
    w.z = (s4.z == m) ? 1.f : 0.f;
    w.w = (s4.w == m) ? 1.f : 0.f;
    asn4[i] = w;
  }
}

// ---------------------------------------------------------------------------
extern "C" void kernel_launch(void* const* d_in, const int* in_sizes, int n_in,
                              void* d_out, int out_size, void* d_ws, size_t ws_size,
                              hipStream_t stream)
{
  const float* points      = (const float*)d_in[0];
  const float* gt_bboxes   = (const float*)d_in[1];
  const int*   gt_labels   = (const int*)d_in[2];
  const float* pred_bboxes = (const float*)d_in[3];
  const float* pred_scores = (const float*)d_in[4];
  const int*   gt_mask     = (const int*)d_in[5];
  float* out = (float*)d_out;

  char* ws = (char*)d_ws;
  unsigned long long* mikey = (unsigned long long*)ws; ws += (size_t)NB * NK * 8;
  int*   fg0    = (int*)ws;    ws += (size_t)NB * NK * 4;
  int*   slot   = (int*)ws;    ws += (size_t)NB * NK * 4;
  float* sval   = (float*)ws;  ws += (size_t)NB * NK * 4;
  int*   flag   = (int*)ws;    ws += 256;
  int*   tki    = (int*)ws;    ws += (size_t)NB * NM * NT * 4;
  float* tkv    = (float*)ws;  ws += (size_t)NB * NM * NT * 4;
  float* ovmaxp = (float*)ws;  ws += (size_t)NB * NM * 4;
  float* candv  = (float*)ws;  ws += (size_t)NB * NM * NQ * NT * 4;
  int*   candi  = (int*)ws;    ws += (size_t)NB * NM * NQ * NT * 4;
  float* ovmaxq = (float*)ws;  ws += (size_t)NB * NM * NQ * 4;

  // init workspace (own kernel: graph-captured hipMemsetAsync runs at 23 GB/s)
  kZ<<<1024, 256, 0, stream>>>(mikey, fg0, slot, flag);

  dim3 gA(NB * NM, NQ);
  kA<<<gA, 256, 0, stream>>>(points, gt_bboxes, gt_labels, pred_bboxes,
                             pred_scores, gt_mask, out, candv, candi,
                             ovmaxq, mikey);

  kA2<<<NB * NM, 64, 0, stream>>>(candv, candi, ovmaxq, ovmaxp, tki, tkv,
                                  fg0, flag);

  kS<<<NB, 256, 0, stream>>>(tki, tkv, ovmaxp, mikey, flag, slot, sval);

  kWt<<<2048, 256, 0, stream>>>(slot, sval, gt_labels, gt_bboxes, out);
  kWa<<<2048, 256, 0, stream>>>(slot, out);
}

// Round 7
// 111.297 us; speedup vs baseline: 1.4470x; 1.4470x over previous
//
#include <hip/hip_runtime.h>
#include <math.h>

// Problem constants (match reference)
constexpr int NB = 32, NM = 64, NK = 8400, NC = 80, NT = 15;
constexpr int NQ = 4, KQ = 2100;       // k split into 4 quarters of 2100
constexpr float FEPS = 1e-7f;

// Output layout: [tso | tgt_bboxes | assign | overlaps | fg], all float32
constexpr size_t OUT_TSO = 0;
constexpr size_t OUT_TGT = (size_t)NB * NK * NC;            // 21504000
constexpr size_t OUT_ASN = OUT_TGT + (size_t)NB * NK * 4;   // 22579200
constexpr size_t OUT_OVL = OUT_ASN + (size_t)NB * NM * NK;  // 39782400
constexpr size_t OUT_FG  = OUT_OVL + (size_t)NB * NM * NK;  // 56985600

// ---------------------------------------------------------------------------
// kFill: zero all of d_out (float4 streaming stores, harness-fill pattern)
// + init workspace (mikey=0, fg0=0, flag=0). Replaces graph-captured
// hipMemsetAsync (which ran at 23 GB/s for small sizes).
// ---------------------------------------------------------------------------
__global__ __launch_bounds__(256) void kFill(float4* __restrict__ out4, int n4,
                                             unsigned long long* __restrict__ mikey,
                                             int* __restrict__ fg0,
                                             int* __restrict__ flag)
{
  const int tid = blockIdx.x * 256 + threadIdx.x;
  const int stride = gridDim.x * 256;
  const float4 z = {0.f, 0.f, 0.f, 0.f};
  for (int i = tid; i < n4; i += stride) out4[i] = z;
  for (int i = tid; i < NB * NK; i += stride) { mikey[i] = 0ULL; fg0[i] = 0; }
  if (tid == 0) *flag = 0;
}

// ---------------------------------------------------------------------------
// kA: one block per (b,m,quarter).
//   pass 1: point-in-box test -> positive-k list (~3-5%)
//   pass 2: CIoU on positives only -> SCATTERED overlaps writes (zeros come
//           from kFill), mi atomicMax key, am candidates in LDS
//   tail  : per-quarter top-15 (value desc, idx asc) by wave-0 butterfly
// ---------------------------------------------------------------------------
__global__ __launch_bounds__(256) void kA(
    const float* __restrict__ points, const float* __restrict__ gt_bboxes,
    const int* __restrict__ gt_labels, const float* __restrict__ pred_bboxes,
    const float* __restrict__ pred_scores, const int* __restrict__ gt_mask,
    float* __restrict__ out, float* __restrict__ candv, int* __restrict__ candi,
    float* __restrict__ ovmaxq, unsigned long long* __restrict__ mikey)
{
  __shared__ int   s_pos[KQ];    // 8.4 KB positive-k list
  __shared__ float s_cv[KQ];     // 8.4 KB candidate am
  __shared__ int   s_ci[KQ];     // 8.4 KB candidate k
  __shared__ int   s_np, s_cnt;
  __shared__ float s_m[4];

  const int bm = blockIdx.x;
  const int q  = blockIdx.y;
  const int b  = bm >> 6;
  const int m  = bm & 63;
  const int t  = threadIdx.x;
  const int wid = t >> 6, lane = t & 63;
  const int kbeg = q * KQ;

  float* cv = candv + (size_t)(bm * NQ + q) * NT;
  int*   ci = candi + (size_t)(bm * NQ + q) * NT;

  const int maskv = gt_mask[bm];
  if (!maskv) {
    if (t == 0) ovmaxq[bm * NQ + q] = 0.f;
    if (t < NT) { cv[t] = 0.f; ci[t] = -1; }
    return;
  }
  if (t == 0) { s_np = 0; s_cnt = 0; }
  __syncthreads();

  const float4 g = *(const float4*)(gt_bboxes + (size_t)bm * 4);
  const int   label = gt_labels[bm];
  const float2* pts = (const float2*)points;

  // pass 1: point-in-box (diff.max(-1) < 1e-6, exact f32 single-subtractions)
  #pragma unroll
  for (int j = 0; j < 9; ++j) {
    const int idx = j * 256 + t;
    if (idx < KQ) {
      const int k = kbeg + idx;
      float2 p = pts[k];
      float dmax = fmaxf(fmaxf(g.x - p.x, g.y - p.y), fmaxf(p.x - g.z, p.y - g.w));
      if (dmax < 1e-6f) { int e = atomicAdd(&s_np, 1); s_pos[e] = k; }
    }
  }
  __syncthreads();
  const int np = s_np;

  const float4* pb = (const float4*)(pred_bboxes + (size_t)b * NK * 4);
  const float*  ps = pred_scores + (size_t)b * NK * NC;
  float* ovl_out = out + OUT_OVL + (size_t)bm * NK;
  unsigned long long* mk = mikey + (size_t)b * NK;

  const float w1 = g.z - g.x, h1 = g.w - g.y;
  const float at1 = atanf(w1 / (h1 + FEPS));
  const float area1 = w1 * h1;
  const float CV = (float)(4.0 / (M_PI * M_PI));
  const float ONE_EPS = (float)(1.0 + 1e-7);

  float lmax = 0.f;
  for (int e = t; e < np; e += 256) {
    const int k = s_pos[e];
    float4 qb = pb[k];
    float w2 = qb.z - qb.x, h2 = qb.w - qb.y;
    float iw = fmaxf(fminf(g.z, qb.z) - fmaxf(g.x, qb.x), 0.f);
    float ih = fmaxf(fminf(g.w, qb.w) - fmaxf(g.y, qb.y), 0.f);
    float inter = iw * ih;
    float uni = area1 + w2 * h2 - inter + FEPS;
    float iou = inter / uni;
    float cw = fmaxf(g.z, qb.z) - fminf(g.x, qb.x);
    float ch = fmaxf(g.w, qb.w) - fminf(g.y, qb.y);
    float c2 = cw * cw + ch * ch + FEPS;
    float ex = qb.x + qb.z - g.x - g.z;
    float ey = qb.y + qb.w - g.y - g.w;
    float rho2 = (ex * ex + ey * ey) * 0.25f;
    float dat = atanf(w2 / (h2 + FEPS)) - at1;
    float v = CV * dat * dat;
    float alpha = v / (v - iou + ONE_EPS);
    float ciou = iou - (rho2 / c2 + alpha * v);
    float ov = fmaxf(ciou, 0.f);
    if (ov > 0.f) {
      ovl_out[k] = ov;                                  // zeros come from kFill
      unsigned long long key =
          ((unsigned long long)__float_as_uint(ov) << 32) |
          (unsigned long long)(NM - 1 - m);             // value desc, first-m tie
      atomicMax(&mk[k], key);
      lmax = fmaxf(lmax, ov);
      float ts = ps[(size_t)k * NC + label];
      float o2 = ov * ov;
      float am = ts * (o2 * o2 * o2);                   // ts**1 * ov**6
      if (am > 1e-9f) {                                 // below cutoff never selected
        int p2 = atomicAdd(&s_cnt, 1);
        s_cv[p2] = am; s_ci[p2] = k;
      }
    }
  }

  // partial row-max of overlaps
  float mv = lmax;
  #pragma unroll
  for (int d = 1; d < 64; d <<= 1) mv = fmaxf(mv, __shfl_xor(mv, d));
  if (lane == 0) s_m[wid] = mv;
  __syncthreads();   // finalizes s_cnt/s_cv/s_ci too
  if (t == 0)
    ovmaxq[bm * NQ + q] = fmaxf(fmaxf(s_m[0], s_m[1]), fmaxf(s_m[2], s_m[3]));

  if (wid != 0) return;           // extraction: wave 0 only
  const int n = s_cnt;

  // per-lane best over lane-strided slots; key = fbits(v)<<32 | ~ki
  unsigned long long bkey = 0; int bslot = -1;
  for (int e = lane; e < n; e += 64) {
    float v = s_cv[e];
    unsigned long long key =
        ((unsigned long long)__float_as_uint(v) << 32) |
        (unsigned long long)(0xFFFFFFFFu - (unsigned)s_ci[e]);
    if (key > bkey) { bkey = key; bslot = e; }
  }

  int it = 0;
  for (; it < NT; ++it) {
    unsigned long long wkey = bkey;
    #pragma unroll
    for (int d = 1; d < 64; d <<= 1) {
      unsigned long long ok = __shfl_xor(wkey, d);
      if (ok > wkey) wkey = ok;
    }
    if (wkey == 0) break;         // all consumed
    if (lane == 0) {
      cv[it] = __uint_as_float((unsigned)(wkey >> 32));
      ci[it] = (int)(0xFFFFFFFFu - (unsigned)wkey);
    }
    if (bkey == wkey) {           // unique winner (ki unique)
      s_cv[bslot] = -1.f;
      bkey = 0; bslot = -1;
      for (int e = lane; e < n; e += 64) {
        float v = s_cv[e];
        if (v >= 0.f) {
          unsigned long long key =
              ((unsigned long long)__float_as_uint(v) << 32) |
              (unsigned long long)(0xFFFFFFFFu - (unsigned)s_ci[e]);
          if (key > bkey) { bkey = key; bslot = e; }
        }
      }
    }
  }
  if (lane == 0)
    for (int r = it; r < NT; ++r) { cv[r] = 0.f; ci[r] = -1; }
}

// ---------------------------------------------------------------------------
// kA2: one wave per (b,m): merge 4x15 quarter candidates -> global top-15
// (identical ordering to single-pass iterative argmax), fg0/flag atomics,
// ovmax merge.
// ---------------------------------------------------------------------------
__global__ __launch_bounds__(64) void kA2(
    const float* __restrict__ candv, const int* __restrict__ candi,
    const float* __restrict__ ovmaxq, float* __restrict__ ovmaxp,
    int* __restrict__ tki, float* __restrict__ tkv,
    int* __restrict__ fg0, int* __restrict__ flag)
{
  __shared__ int   s_wi[NT];
  __shared__ float s_wv[NT];
  const int bm = blockIdx.x;
  const int b  = bm >> 6;
  const int lane = threadIdx.x;

  if (lane == 0) {
    const float* om = ovmaxq + bm * NQ;
    ovmaxp[bm] = fmaxf(fmaxf(om[0], om[1]), fmaxf(om[2], om[3]));
  }

  unsigned long long bkey = 0;
  if (lane < NQ * NT) {
    int ki = candi[(size_t)bm * NQ * NT + lane];
    if (ki >= 0) {
      float v = candv[(size_t)bm * NQ * NT + lane];
      bkey = ((unsigned long long)__float_as_uint(v) << 32) |
             (unsigned long long)(0xFFFFFFFFu - (unsigned)ki);
    }
  }

  int nf = 0;
  for (int it = 0; it < NT; ++it) {
    unsigned long long wkey = bkey;
    #pragma unroll
    for (int d = 1; d < 64; d <<= 1) {
      unsigned long long ok = __shfl_xor(wkey, d);
      if (ok > wkey) wkey = ok;
    }
    if (wkey == 0) break;
    if (bkey == wkey) {           // unique winner stores round result
      s_wv[it] = __uint_as_float((unsigned)(wkey >> 32));
      s_wi[it] = (int)(0xFFFFFFFFu - (unsigned)wkey);
      bkey = 0;
    }
    nf = it + 1;
  }
  __syncthreads();

  if (lane < NT) {
    if (lane < nf) {
      int fi = s_wi[lane];
      tki[bm * NT + lane] = fi;
      tkv[bm * NT + lane] = s_wv[lane];
      int old = atomicAdd(&fg0[(size_t)b * NK + fi], 1);
      if (old >= 1) atomicOr(flag, 1);
    } else {
      tki[bm * NT + lane] = -1;
      tkv[bm * NT + lane] = 0.f;
    }
  }
}

// ---------------------------------------------------------------------------
// kF: per (b, 256-k tile). Post-filter fg is 0/1 => unique entry per k.
// Keep-filter + rowmax + LDS slot scatter; writes dense fg + tgt (float4),
// scattered assign ones and single tso element per hit. Zeros from kFill.
// ---------------------------------------------------------------------------
__global__ __launch_bounds__(256) void kF(
    const float* __restrict__ gt_bboxes, const int* __restrict__ gt_labels,
    const int* __restrict__ tki, const float* __restrict__ tkv,
    const float* __restrict__ ovmaxp, const unsigned long long* __restrict__ mikey,
    const int* __restrict__ flagp, float* __restrict__ out)
{
  __shared__ int    s_tki[NM * NT];
  __shared__ float  s_tkv[NM * NT];
  __shared__ unsigned char s_keep[NM * NT];
  __shared__ float  s_rowmax[NM];
  __shared__ float  s_ovmax[NM];
  __shared__ int    s_label[NM];
  __shared__ float4 s_gtb[NM];
  __shared__ int    s_mk[256];
  __shared__ float  s_sv[256];

  const int b  = blockIdx.y;
  const int k0 = blockIdx.x * 256;
  const int t  = threadIdx.x;
  const int flag = *flagp;

  for (int e = t; e < NM * NT; e += 256) {
    s_tki[e] = tki[b * NM * NT + e];
    s_tkv[e] = tkv[b * NM * NT + e];
  }
  if (t < NM) {
    s_ovmax[t] = ovmaxp[b * NM + t];
    s_label[t] = gt_labels[b * NM + t];
    s_gtb[t] = *(const float4*)(gt_bboxes + (size_t)(b * NM + t) * 4);
  }
  s_mk[t] = -1;
  s_sv[t] = 0.f;
  __syncthreads();

  // keep flags (parallel over all 960 entries)
  for (int e = t; e < NM * NT; e += 256) {
    const int idx = s_tki[e];
    bool kp = (idx >= 0);
    if (kp && flag) {
      unsigned long long key = mikey[(size_t)b * NK + idx];
      int mi = NM - 1 - (int)(key & 0xFFFFFFFFull);   // key>0 for valid entries
      kp = (mi == e / NT);
    }
    s_keep[e] = kp;
  }
  __syncthreads();

  // post-filter row max of am over surviving entries
  if (t < NM) {
    float r = 0.f;
    for (int j = 0; j < NT; ++j) {
      const int e = t * NT + j;
      if (s_keep[e]) r = fmaxf(r, s_tkv[e]);
    }
    s_rowmax[t] = r;
  }
  __syncthreads();

  // scatter kept entries whose idx lands in this tile (unique per k);
  // write the assign ones directly (zeros from kFill)
  for (int e = t; e < NM * NT; e += 256) {
    if (!s_keep[e]) continue;
    const int idx = s_tki[e];
    if (idx < k0 || idx >= k0 + 256) continue;
    const int m = e / NT;
    s_mk[idx - k0] = m;
    s_sv[idx - k0] = s_tkv[e] / (s_rowmax[m] + 1e-9f) * s_ovmax[m];
    out[OUT_ASN + (size_t)(b * NM + m) * NK + idx] = 1.f;
  }
  __syncthreads();

  const int k = k0 + t;
  if (k < NK) {
    const int mk2 = s_mk[t];
    const int tb = (mk2 >= 0) ? mk2 : 0;   // argmax of all-zero column -> 0
    out[OUT_FG + (size_t)b * NK + k] = (mk2 >= 0) ? 1.f : 0.f;
    *(float4*)(out + OUT_TGT + (size_t)(b * NK + k) * 4) = s_gtb[tb];
    if (mk2 >= 0)
      out[OUT_TSO + (size_t)(b * NK + k) * NC + s_label[mk2]] = s_sv[t];
  }
}

// ---------------------------------------------------------------------------
extern "C" void kernel_launch(void* const* d_in, const int* in_sizes, int n_in,
                              void* d_out, int out_size, void* d_ws, size_t ws_size,
                              hipStream_t stream)
{
  const float* points      = (const float*)d_in[0];
  const float* gt_bboxes   = (const float*)d_in[1];
  const int*   gt_labels   = (const int*)d_in[2];
  const float* pred_bboxes = (const float*)d_in[3];
  const float* pred_scores = (const float*)d_in[4];
  const int*   gt_mask     = (const int*)d_in[5];
  float* out = (float*)d_out;

  char* ws = (char*)d_ws;
  unsigned long long* mikey = (unsigned long long*)ws; ws += (size_t)NB * NK * 8;
  int*   fg0    = (int*)ws;    ws += (size_t)NB * NK * 4;
  int*   flag   = (int*)ws;    ws += 256;
  int*   tki    = (int*)ws;    ws += (size_t)NB * NM * NT * 4;
  float* tkv    = (float*)ws;  ws += (size_t)NB * NM * NT * 4;
  float* ovmaxp = (float*)ws;  ws += (size_t)NB * NM * 4;
  float* candv  = (float*)ws;  ws += (size_t)NB * NM * NQ * NT * 4;
  int*   candi  = (int*)ws;    ws += (size_t)NB * NM * NQ * NT * 4;
  float* ovmaxq = (float*)ws;  ws += (size_t)NB * NM * NQ * 4;

  // zero all outputs + init workspace, one streaming kernel
  kFill<<<8192, 256, 0, stream>>>((float4*)d_out, out_size / 4, mikey, fg0, flag);

  dim3 gA(NB * NM, NQ);
  kA<<<gA, 256, 0, stream>>>(points, gt_bboxes, gt_labels, pred_bboxes,
                             pred_scores, gt_mask, out, candv, candi,
                             ovmaxq, mikey);

  kA2<<<NB * NM, 64, 0, stream>>>(candv, candi, ovmaxq, ovmaxp, tki, tkv,
                                  fg0, flag);

  dim3 g2((NK + 255) / 256, NB);
  kF<<<g2, 256, 0, stream>>>(gt_bboxes, gt_labels, tki, tkv, ovmaxp, mikey,
                             flag, out);
}